// Round 11
// baseline (128.281 us; speedup 1.0000x reference)
//
#include <hip/hip_runtime.h>
#include <hip/hip_bf16.h>

// Problem: features_1 [1,20000,256] f32, features_2 [1,8192,256] f32, map21 [8192] int
#define PP      8192
#define DIM     256
#define DIMP    272              // 256 + 16 pad dims (norm embedding in 4 of them)
#define NKF     17               // K fragments of 16
#define GS      (32 * DIMP)      // 8704 bf16 elems per 32-row group
#define NCHUNK  16               // column chunks (grid.y); chunk = 512 cols
#define TCOLS   16               // 32-col tiles per chunk
#define ROWBLK  512              // rows per main block (4 waves x 4 row-groups)
#define NROWBLK (PP / ROWBLK)    // 16
#define TILEB   (32 * DIMP * 2)  // 17408 B per 32-col B tile
#define NBUF    2                // LDS double buffer

typedef __bf16 bf16_t;
using bf16x8 = __attribute__((ext_vector_type(8))) __bf16;
using bf16x4 = __attribute__((ext_vector_type(4))) __bf16;
using f32x4  = __attribute__((ext_vector_type(4))) float;
using f32x16 = __attribute__((ext_vector_type(16))) float;

typedef __attribute__((address_space(1))) void as1_void;
typedef __attribute__((address_space(3))) void as3_void;

#define C2    20.609929155556618          // 1/(T*ln2): -dist -> log2-domain logit
#define MEXP  (-340.0f)                   // fixed log2 shift (safe: see analysis)
#define COEF  ((float)(-(C2 * 1.4142135623730951) * 8388608.0))  // -C2*sqrt(2)*2^23
#define KBIAS ((float)((127.0 + 340.0) * 8388608.0))             // (127 - MEXP)*2^23
#define LN2   0.6931471805599453f

// ---------------------------------------------------------------------------
// Kernel 1: gather + bf16 convert into frag-major layout + norm-embedding pad
// dims + exact fp32 diagonal logit. Also zero-inits part_l / counters / out.
// One wave per row p; lane covers k = lane*4 .. +3.   (UNCHANGED)
// ---------------------------------------------------------------------------
__global__ __launch_bounds__(256) void nce_prep(
    const float* __restrict__ f1, const float* __restrict__ f2,
    const int* __restrict__ map,
    bf16_t* __restrict__ qb2, bf16_t* __restrict__ kb2,
    float* __restrict__ diag2, float* __restrict__ part_l,
    unsigned* __restrict__ cnt, float* __restrict__ out)
{
    const int tid  = threadIdx.x;
    const int wave = tid >> 6, lane = tid & 63;
    const int p    = blockIdx.x * 4 + wave;
    const int gtid = blockIdx.x * 256 + tid;

    if (gtid < PP) part_l[gtid] = 0.0f;
    if (gtid < NROWBLK) cnt[gtid] = 0u;
    if (gtid == 0) out[0] = 0.0f;

    const int idx = map[p];
    const f32x4 qv = *(const f32x4*)(f1 + (size_t)idx * DIM + lane * 4);
    const f32x4 kv = *(const f32x4*)(f2 + (size_t)p * DIM + lane * 4);

    float qs = qv[0]*qv[0] + qv[1]*qv[1] + qv[2]*qv[2] + qv[3]*qv[3];
    float ks = kv[0]*kv[0] + kv[1]*kv[1] + kv[2]*kv[2] + kv[3]*kv[3];
    const f32x4 dv = qv - kv;
    float ds = dv[0]*dv[0] + dv[1]*dv[1] + dv[2]*dv[2] + dv[3]*dv[3];

    bf16x4 qo, ko;
    #pragma unroll
    for (int i = 0; i < 4; ++i) { qo[i] = (bf16_t)qv[i]; ko[i] = (bf16_t)kv[i]; }

    const int G = p >> 5, l31 = p & 31;
    const int kk = lane >> 2, h = (lane >> 1) & 1, j0 = (lane & 1) * 4;
    const size_t base = (size_t)G * GS;
    const size_t off  = base + (size_t)(kk * 64 + h * 32 + l31) * 8 + j0;
    *(bf16x4*)(qb2 + off) = qo;
    *(bf16x4*)(kb2 + off) = ko;

    #pragma unroll
    for (int s = 32; s > 0; s >>= 1) {
        qs += __shfl_xor(qs, s);
        ks += __shfl_xor(ks, s);
        ds += __shfl_xor(ds, s);
    }

    // Pad frag kk=16 (dims 256..271). q' = [qhi,qlo,1,1,0..], k' = [1,1,khi,klo,0..]
    // so extra-dim dot = -(qs+ks)/2 with bf16 hi/lo split (norm error < 0.01).
    if (lane < 4) {
        const int hh = lane & 1;           // h of the pad block this lane writes
        bf16x8 v;
        #pragma unroll
        for (int i = 0; i < 8; ++i) v[i] = (bf16_t)0.0f;
        if (lane == 0) {                   // q', dims 256..263
            const float qh = -0.5f * qs;
            const bf16_t q1 = (bf16_t)qh;
            v[0] = q1; v[1] = (bf16_t)(qh - (float)q1);
            v[2] = (bf16_t)1.0f; v[3] = (bf16_t)1.0f;
        } else if (lane == 2) {            // k', dims 256..263
            const float kh = -0.5f * ks;
            const bf16_t k1 = (bf16_t)kh;
            v[0] = (bf16_t)1.0f; v[1] = (bf16_t)1.0f;
            v[2] = k1; v[3] = (bf16_t)(kh - (float)k1);
        }
        bf16_t* dstp = (lane < 2) ? qb2 : kb2;
        *(bf16x8*)(dstp + base + (size_t)(1024 + hh * 32 + l31) * 8) = v;
    }
    if (lane == 0)
        diag2[p] = (float)(-C2) * __builtin_amdgcn_sqrtf(ds);  // exact diag, log2
}

// ---------------------------------------------------------------------------
// Stage one 32-col B tile (17408 B, frag-major) into LDS via global_load_lds
// width-16.  4-WAVE version (R6's proven form, verbatim): waves 0-3 load
// 4x1KB each; wave 0 loads the 17th-fragment KB extra (5 loads).
// Safety: every phase ends with vmcnt(0)+lgkmcnt(0)+barrier — tile staged at
// phase-T top is visible entering T+1; the stage has the whole compute phase
// (~3500 cyc) in flight, latency fully hidden.
// ---------------------------------------------------------------------------
__device__ __forceinline__ void stage(const bf16_t* __restrict__ kb2,
                                      int Gc, int wave, int lane, char* dst)
{
    __builtin_assume(wave >= 0 && wave < 4);
    __builtin_assume(lane >= 0 && lane < 64);
    const bf16_t* src = kb2 + (size_t)Gc * GS + wave * 512 + lane * 8;
    char* d = dst + wave * 1024;
    #pragma unroll
    for (int j = 0; j < 4; ++j)
        __builtin_amdgcn_global_load_lds((const as1_void*)(src + j * 2048),
                                         (as3_void*)(d + j * 4096), 16, 0, 0);
    if (wave == 0)   // last 1 KB (17th fragment block)
        __builtin_amdgcn_global_load_lds((const as1_void*)(src + 4 * 2048),
                                         (as3_void*)(d + 4 * 4096), 16, 0, 0);
}

// ---------------------------------------------------------------------------
// ROUND-11: RG=4.  R9/R10's 512-thread 2-waves/SIMD bet failed to launch
// twice (its (512,2) bound demands <=256 total regs vs ~280 actual).  The
// occupancy data across rounds shows RG=2's real footprint is ~280 regs ->
// 1 wave/SIMD always.  So: stay 1 wave/SIMD, amortize harder instead.
// Wave owns FOUR 32-row groups:
//   - one ds_read_b128 feeds 4 MFMAs (128 cyc matrix work / 12 cyc read);
//     one-ahead B prefetch keeps the lgkm wait off the critical path.
//   - 4 natural acc chains (one per group), same-chain spacing 4 MFMAs =
//     128 cyc -> dependent-MFMA stalls gone without extra acc sets.
//   - MFMA section 68x32 = 2176 cyc/phase vs serial EPI ~900 + barrier ~400:
//     phase ~3500 cyc for 4 groups (R6: 3975 for 2) -> ~2x per-output.
// Regs: A 272 + acc 64 + l 64 + temps ~40 = ~440 <= 512 -> fits at (256,1).
// Skeleton (stage -> ds+MFMA -> EPI -> full-drain barrier) = R6's, proven.
// ---------------------------------------------------------------------------
#define PHASE(DOPRE, T)                                                        \
  do {                                                                         \
    if (DOPRE) stage(kb2, c0g + (T) + 1, wave, lane, smem[((T) + 1) & 1]);     \
    const bf16_t* bp = (const bf16_t*)smem[(T) & 1] + lane * 8;                \
    f32x16 acc0 = {0,0,0,0,0,0,0,0,0,0,0,0,0,0,0,0};                          \
    f32x16 acc1 = {0,0,0,0,0,0,0,0,0,0,0,0,0,0,0,0};                          \
    f32x16 acc2 = {0,0,0,0,0,0,0,0,0,0,0,0,0,0,0,0};                          \
    f32x16 acc3 = {0,0,0,0,0,0,0,0,0,0,0,0,0,0,0,0};                          \
    bf16x8 bc = *(const bf16x8*)bp;                                            \
    _Pragma("unroll")                                                          \
    for (int kk = 0; kk < NKF; ++kk) {                                         \
        const bf16x8 bn = (kk + 1 < NKF)                                       \
            ? *(const bf16x8*)(bp + (kk + 1) * 512) : bc;                      \
        acc0 = __builtin_amdgcn_mfma_f32_32x32x16_bf16(a0[kk], bc, acc0,0,0,0);\
        acc1 = __builtin_amdgcn_mfma_f32_32x32x16_bf16(a1[kk], bc, acc1,0,0,0);\
        acc2 = __builtin_amdgcn_mfma_f32_32x32x16_bf16(a2[kk], bc, acc2,0,0,0);\
        acc3 = __builtin_amdgcn_mfma_f32_32x32x16_bf16(a3[kk], bc, acc3,0,0,0);\
        bc = bn;                                                               \
    }                                                                          \
    /* acc = -dist^2/2.  2^(lg-MEXP) bitcast trick; negative -> clamp 0 */     \
    _Pragma("unroll")                                                          \
    for (int i = 0; i < 16; ++i) {                                             \
        const float t0 = __builtin_amdgcn_sqrtf(-acc0[i]);                     \
        l0[i] += __uint_as_float((unsigned)fmaxf(fmaf(t0, COEF, KBIAS), 0.0f));\
        const float t1 = __builtin_amdgcn_sqrtf(-acc1[i]);                     \
        l1[i] += __uint_as_float((unsigned)fmaxf(fmaf(t1, COEF, KBIAS), 0.0f));\
        const float t2 = __builtin_amdgcn_sqrtf(-acc2[i]);                     \
        l2[i] += __uint_as_float((unsigned)fmaxf(fmaf(t2, COEF, KBIAS), 0.0f));\
        const float t3 = __builtin_amdgcn_sqrtf(-acc3[i]);                     \
        l3[i] += __uint_as_float((unsigned)fmaxf(fmaf(t3, COEF, KBIAS), 0.0f));\
    }                                                                          \
    asm volatile("s_waitcnt vmcnt(0) lgkmcnt(0)\n\ts_barrier" ::: "memory");   \
  } while (0)

// ---------------------------------------------------------------------------
// Kernel 2: fused (QK' GEMM -> -dist^2/2) + fixed-shift exp2 accumulation +
// cross-block merge via atomicAdd + last-block final loss reduction.
// Block = 4 waves (256 threads) = 512 rows; wave = 128 rows (4 groups) x 32
// cols.  Grid 16x16 = 256 blocks = 1 block/CU.  XCD swizzle: each XCD owns
// 4 rb x 8 cy (A 2.2 MB + B 2.2 MB working set, mostly L2-resident).
// ---------------------------------------------------------------------------
__global__ __launch_bounds__(256, 1) void nce_main(
    const bf16_t* __restrict__ qb2, const bf16_t* __restrict__ kb2,
    const float* __restrict__ diag2, float* __restrict__ part_l,
    unsigned* __restrict__ cnt, float* __restrict__ out)
{
    const int tid  = threadIdx.x, wave = tid >> 6, lane = tid & 63;
    const int l31  = lane & 31, h = lane >> 5;

    // bijective XCD swizzle: lin%8 = XCD (HW round-robin); XCD (xr,xc) owns
    // rb in [xr*4,xr*4+4) x cy in [xc*8,xc*8+8)  (xr=xcd&3, xc=xcd>>2)
    const int lin = blockIdx.x + (blockIdx.y << 4);   // gridDim.x = 16
    const int xcd = lin & 7, idx = lin >> 3;          // idx 0..31
    const int rb  = (xcd & 3) * 4 + (idx & 3);        // row-block 0..15
    const int cy  = (xcd >> 2) * 8 + (idx >> 2);      // chunk 0..15
    const int G0  = rb * 16 + wave * 4;               // wave's first 32-row group
    const int c0g = cy * TCOLS;                       // first col-group of chunk

    __shared__ __align__(16) char smem[NBUF][TILEB];
    __shared__ int s_last;
    __shared__ float red[4];

    // prologue: stage tile 0, then A-fragment loads (all drained together)
    stage(kb2, c0g, wave, lane, smem[0]);

    bf16x8 a0[NKF], a1[NKF], a2[NKF], a3[NKF];   // 4 x 17 x 4 = 272 regs
    {
        const bf16_t* ap = qb2 + (size_t)G0 * GS + lane * 8;
        #pragma unroll
        for (int kk = 0; kk < NKF; ++kk) {
            a0[kk] = *(const bf16x8*)(ap + kk * 512);
            a1[kk] = *(const bf16x8*)(ap + GS + kk * 512);
            a2[kk] = *(const bf16x8*)(ap + 2 * GS + kk * 512);
            a3[kk] = *(const bf16x8*)(ap + 3 * GS + kk * 512);
        }
    }

    float l0[16], l1[16], l2[16], l3[16];
    #pragma unroll
    for (int i = 0; i < 16; ++i) { l0[i]=0.0f; l1[i]=0.0f; l2[i]=0.0f; l3[i]=0.0f; }

    // tile0 + A in place for everyone
    asm volatile("s_waitcnt vmcnt(0) lgkmcnt(0)\n\ts_barrier" ::: "memory");

    // steady state (rolled — full unroll spilled in round 2)
    #pragma unroll 1
    for (int t = 0; t < TCOLS - 1; ++t)
        PHASE(true, t);
    PHASE(false, TCOLS - 1);   // drain tail

    // sum l across the 32 column-lanes (plain adds — fixed shift, no max merge)
    #pragma unroll
    for (int s = 1; s < 32; s <<= 1) {
        #pragma unroll
        for (int i = 0; i < 16; ++i) {
            l0[i] += __shfl_xor(l0[i], s);
            l1[i] += __shfl_xor(l1[i], s);
            l2[i] += __shfl_xor(l2[i], s);
            l3[i] += __shfl_xor(l3[i], s);
        }
    }

    if (l31 == 0) {
        #pragma unroll
        for (int i = 0; i < 16; ++i) {
            const int r = (i & 3) + 8 * (i >> 2) + 4 * h;
            atomicAdd(&part_l[(G0 + 0) * 32 + r], l0[i]);
            atomicAdd(&part_l[(G0 + 1) * 32 + r], l1[i]);
            atomicAdd(&part_l[(G0 + 2) * 32 + r], l2[i]);
            atomicAdd(&part_l[(G0 + 3) * 32 + r], l3[i]);
        }
    }

    __syncthreads();
    if (tid == 0) {
        __threadfence();
        s_last = (atomicAdd(&cnt[rb], 1u) == NCHUNK - 1) ? 1 : 0;
    }
    __syncthreads();
    if (s_last) {
        // all 16 chunk-blocks of this row-block done: finalize 512 rows
        // (256 threads, 2 rows each)
        const int rowA = rb * ROWBLK + tid;
        const int rowB = rowA + 256;
        const float lfA = atomicAdd(&part_l[rowA], 0.0f);   // coherent read
        const float lfB = atomicAdd(&part_l[rowB], 0.0f);
        float v = (MEXP + __builtin_amdgcn_logf(lfA) - diag2[rowA])
                + (MEXP + __builtin_amdgcn_logf(lfB) - diag2[rowB]);
        #pragma unroll
        for (int s = 1; s < 64; s <<= 1) v += __shfl_xor(v, s);
        if (lane == 0) red[wave] = v;
        __syncthreads();
        if (tid == 0)
            atomicAdd(out, (red[0] + red[1] + red[2] + red[3]) * (LN2 / (float)PP));
    }
}

// ---------------------------------------------------------------------------
extern "C" void kernel_launch(void* const* d_in, const int* in_sizes, int n_in,
                              void* d_out, int out_size, void* d_ws, size_t ws_size,
                              hipStream_t stream)
{
    const float* f1  = (const float*)d_in[0];   // [20000,256] f32
    const float* f2  = (const float*)d_in[1];   // [8192,256] f32
    const int*   map = (const int*)d_in[2];     // [8192] int
    float* out = (float*)d_out;

    // workspace layout (~8.98 MB)
    char* ws = (char*)d_ws;
    bf16_t*   qb2    = (bf16_t*)ws;                           // 256*8704*2 B
    bf16_t*   kb2    = qb2 + (size_t)256 * GS;                // 256*8704*2 B
    float*    diag2  = (float*)(ws + 2ull * 256 * GS * sizeof(bf16_t));
    float*    part_l = diag2 + PP;
    unsigned* cnt    = (unsigned*)(part_l + PP);

    nce_prep<<<PP / 4, 256, 0, stream>>>(f1, f2, map, qb2, kb2, diag2,
                                         part_l, cnt, out);
    nce_main<<<dim3(NROWBLK, NCHUNK), 256, 0, stream>>>(qb2, kb2, diag2,
                                                        part_l, cnt, out);
}

// Round 12
// 121.967 us; speedup vs baseline: 1.0518x; 1.0518x over previous
//
#include <hip/hip_runtime.h>
#include <hip/hip_bf16.h>

// Problem: features_1 [1,20000,256] f32, features_2 [1,8192,256] f32, map21 [8192] int
#define PP      8192
#define DIM     256
#define DIMP    272              // 256 + 16 pad dims (norm embedding in 4 of them)
#define NKF     17               // K fragments of 16
#define GS      (32 * DIMP)      // 8704 bf16 elems per 32-row group
#define NCHUNK  8                // column chunks (grid.y); chunk = 1024 cols
#define PHASES  16               // phases per chunk; phase = 64 cols (2 tiles)
#define ROWBLK  128              // rows per main block (4 waves x 1 row-group)
#define NROWBLK (PP / ROWBLK)    // 64
#define TILEB   (32 * DIMP * 2)  // 17408 B per 32-col B tile
#define NBUF    2                // LDS double buffer (of 2-tile pairs)

typedef __bf16 bf16_t;
using bf16x8 = __attribute__((ext_vector_type(8))) __bf16;
using bf16x4 = __attribute__((ext_vector_type(4))) __bf16;
using f32x4  = __attribute__((ext_vector_type(4))) float;
using f32x16 = __attribute__((ext_vector_type(16))) float;

typedef __attribute__((address_space(1))) void as1_void;
typedef __attribute__((address_space(3))) void as3_void;

#define C2    20.609929155556618          // 1/(T*ln2): -dist -> log2-domain logit
#define MEXP  (-340.0f)                   // fixed log2 shift (safe: see analysis)
#define COEF  ((float)(-(C2 * 1.4142135623730951) * 8388608.0))  // -C2*sqrt(2)*2^23
#define KBIAS ((float)((127.0 + 340.0) * 8388608.0))             // (127 - MEXP)*2^23
#define LN2   0.6931471805599453f

// ---------------------------------------------------------------------------
// Kernel 1: gather + bf16 convert into frag-major layout + norm-embedding pad
// dims + exact fp32 diagonal logit. Also zero-inits part_l / counters / out.
// One wave per row p; lane covers k = lane*4 .. +3.   (UNCHANGED)
// ---------------------------------------------------------------------------
__global__ __launch_bounds__(256) void nce_prep(
    const float* __restrict__ f1, const float* __restrict__ f2,
    const int* __restrict__ map,
    bf16_t* __restrict__ qb2, bf16_t* __restrict__ kb2,
    float* __restrict__ diag2, float* __restrict__ part_l,
    unsigned* __restrict__ cnt, float* __restrict__ out)
{
    const int tid  = threadIdx.x;
    const int wave = tid >> 6, lane = tid & 63;
    const int p    = blockIdx.x * 4 + wave;
    const int gtid = blockIdx.x * 256 + tid;

    if (gtid < PP) part_l[gtid] = 0.0f;
    if (gtid < NROWBLK) cnt[gtid] = 0u;
    if (gtid == 0) out[0] = 0.0f;

    const int idx = map[p];
    const f32x4 qv = *(const f32x4*)(f1 + (size_t)idx * DIM + lane * 4);
    const f32x4 kv = *(const f32x4*)(f2 + (size_t)p * DIM + lane * 4);

    float qs = qv[0]*qv[0] + qv[1]*qv[1] + qv[2]*qv[2] + qv[3]*qv[3];
    float ks = kv[0]*kv[0] + kv[1]*kv[1] + kv[2]*kv[2] + kv[3]*kv[3];
    const f32x4 dv = qv - kv;
    float ds = dv[0]*dv[0] + dv[1]*dv[1] + dv[2]*dv[2] + dv[3]*dv[3];

    bf16x4 qo, ko;
    #pragma unroll
    for (int i = 0; i < 4; ++i) { qo[i] = (bf16_t)qv[i]; ko[i] = (bf16_t)kv[i]; }

    const int G = p >> 5, l31 = p & 31;
    const int kk = lane >> 2, h = (lane >> 1) & 1, j0 = (lane & 1) * 4;
    const size_t base = (size_t)G * GS;
    const size_t off  = base + (size_t)(kk * 64 + h * 32 + l31) * 8 + j0;
    *(bf16x4*)(qb2 + off) = qo;
    *(bf16x4*)(kb2 + off) = ko;

    #pragma unroll
    for (int s = 32; s > 0; s >>= 1) {
        qs += __shfl_xor(qs, s);
        ks += __shfl_xor(ks, s);
        ds += __shfl_xor(ds, s);
    }

    // Pad frag kk=16 (dims 256..271). q' = [qhi,qlo,1,1,0..], k' = [1,1,khi,klo,0..]
    // so extra-dim dot = -(qs+ks)/2 with bf16 hi/lo split (norm error < 0.01).
    if (lane < 4) {
        const int hh = lane & 1;           // h of the pad block this lane writes
        bf16x8 v;
        #pragma unroll
        for (int i = 0; i < 8; ++i) v[i] = (bf16_t)0.0f;
        if (lane == 0) {                   // q', dims 256..263
            const float qh = -0.5f * qs;
            const bf16_t q1 = (bf16_t)qh;
            v[0] = q1; v[1] = (bf16_t)(qh - (float)q1);
            v[2] = (bf16_t)1.0f; v[3] = (bf16_t)1.0f;
        } else if (lane == 2) {            // k', dims 256..263
            const float kh = -0.5f * ks;
            const bf16_t k1 = (bf16_t)kh;
            v[0] = (bf16_t)1.0f; v[1] = (bf16_t)1.0f;
            v[2] = k1; v[3] = (bf16_t)(kh - (float)k1);
        }
        bf16_t* dstp = (lane < 2) ? qb2 : kb2;
        *(bf16x8*)(dstp + base + (size_t)(1024 + hh * 32 + l31) * 8) = v;
    }
    if (lane == 0)
        diag2[p] = (float)(-C2) * __builtin_amdgcn_sqrtf(ds);  // exact diag, log2
}

// ---------------------------------------------------------------------------
// Stage one 32-col B tile (17408 B, frag-major) into LDS via global_load_lds
// width-16.  4-WAVE form (R6, proven): waves 0-3 load 4x1KB each; wave 0
// loads the 17th-fragment KB extra.  Full vmcnt(0) drain before each barrier
// (proven-safe skeleton; the stage has the whole compute phase in flight).
// ---------------------------------------------------------------------------
__device__ __forceinline__ void stage(const bf16_t* __restrict__ kb2,
                                      int Gc, int wave, int lane, char* dst)
{
    __builtin_assume(wave >= 0 && wave < 4);
    __builtin_assume(lane >= 0 && lane < 64);
    const bf16_t* src = kb2 + (size_t)Gc * GS + wave * 512 + lane * 8;
    char* d = dst + wave * 1024;
    #pragma unroll
    for (int j = 0; j < 4; ++j)
        __builtin_amdgcn_global_load_lds((const as1_void*)(src + j * 2048),
                                         (as3_void*)(d + j * 4096), 16, 0, 0);
    if (wave == 0)   // last 1 KB (17th fragment block)
        __builtin_amdgcn_global_load_lds((const as1_void*)(src + 4 * 2048),
                                         (as3_void*)(d + 4 * 4096), 16, 0, 0);
}

// ---------------------------------------------------------------------------
// ROUND-12: the 24-28% MfmaUtil band across FOUR structures (RG=1/2/4, 1-4
// chains, counted/drained vmcnt) is issue-stream serialization at 1
// wave/SIMD: a single in-order stream puts every lgkm wait / EPI op /
// barrier in front of the next MFMA issue.  (LDS-pipe model refuted by
// recomputation: R4's cap was ~66%, not 25%.)  Fix = >=2 DESYNCED waves
// per SIMD, which requires a cheap wave:
//   wave = 32 rows x 64 cols (2 B col-tiles, same A group):
//     a[17]=68 regs (was 136), acc 32, l[16]=16 (col-tiles share rows ->
//     one exp-sum), temps ~30  => ~150 regs -> 2-3 waves/SIMD.
//   block = 4 waves = 128 rows; phase stages 2 tiles (69.6 KB LDS) ->
//     exactly 2 blocks/CU (LDS-capped) -> 2 waves/SIMD from DIFFERENT
//     blocks with independent barriers (true desync, unlike within-block).
//   Per phase per wave: 34 ds_read + 34 MFMA (1:1) -> LDS-pipe cap ~66%.
// Same MFMA count/output as R6; only the resource shape changed.
// ---------------------------------------------------------------------------
#define PHASE(DOPRE, T)                                                        \
  do {                                                                         \
    if (DOPRE) {                                                               \
        stage(kb2, c0g + 2 * ((T) + 1),     wave, lane, smem[((T)+1) & 1][0]); \
        stage(kb2, c0g + 2 * ((T) + 1) + 1, wave, lane, smem[((T)+1) & 1][1]); \
    }                                                                          \
    const bf16_t* bp0 = (const bf16_t*)smem[(T) & 1][0] + lane * 8;            \
    const bf16_t* bp1 = (const bf16_t*)smem[(T) & 1][1] + lane * 8;            \
    f32x16 acc0 = {0,0,0,0,0,0,0,0,0,0,0,0,0,0,0,0};                          \
    f32x16 acc1 = {0,0,0,0,0,0,0,0,0,0,0,0,0,0,0,0};                          \
    _Pragma("unroll")                                                          \
    for (int kk = 0; kk < NKF; ++kk) {                                         \
        const bf16x8 b0 = *(const bf16x8*)(bp0 + kk * 512);                    \
        const bf16x8 b1 = *(const bf16x8*)(bp1 + kk * 512);                    \
        acc0 = __builtin_amdgcn_mfma_f32_32x32x16_bf16(a[kk], b0, acc0,0,0,0); \
        acc1 = __builtin_amdgcn_mfma_f32_32x32x16_bf16(a[kk], b1, acc1,0,0,0); \
    }                                                                          \
    /* acc = -dist^2/2.  2^(lg-MEXP) bitcast trick; negative -> clamp 0.   */  \
    /* Both col-tiles belong to the SAME rows -> merge into one l[].       */  \
    _Pragma("unroll")                                                          \
    for (int i = 0; i < 16; ++i) {                                             \
        const float t0 = __builtin_amdgcn_sqrtf(-acc0[i]);                     \
        const float u0 = fmaxf(fmaf(t0, COEF, KBIAS), 0.0f);                   \
        const float t1 = __builtin_amdgcn_sqrtf(-acc1[i]);                     \
        const float u1 = fmaxf(fmaf(t1, COEF, KBIAS), 0.0f);                   \
        l[i] += __uint_as_float((unsigned)u0) + __uint_as_float((unsigned)u1); \
    }                                                                          \
    asm volatile("s_waitcnt vmcnt(0) lgkmcnt(0)\n\ts_barrier" ::: "memory");   \
  } while (0)

// ---------------------------------------------------------------------------
// Kernel 2: fused (QK' GEMM -> -dist^2/2) + fixed-shift exp2 accumulation +
// cross-block merge via atomicAdd + last-block final loss reduction.
// Block = 4 waves (256 threads) = 128 rows; wave = 32 rows x 64 cols.
// Grid 64x8 = 512 blocks = 2 blocks/CU (LDS-capped at ~70 KB each).
// XCD swizzle: each XCD owns 16 rb x 4 cy (A 1.1 MB + B 2.2 MB < 4 MB L2).
// ---------------------------------------------------------------------------
__global__ __launch_bounds__(256, 2) void nce_main(
    const bf16_t* __restrict__ qb2, const bf16_t* __restrict__ kb2,
    const float* __restrict__ diag2, float* __restrict__ part_l,
    unsigned* __restrict__ cnt, float* __restrict__ out)
{
    const int tid  = threadIdx.x, wave = tid >> 6, lane = tid & 63;
    const int l31  = lane & 31, h = lane >> 5;

    // bijective XCD swizzle: lin%8 = XCD (HW round-robin); XCD (xr,xc) owns
    // rb in [xr*16,xr*16+16) x cy in [xc*4,xc*4+4)  (xr=xcd&3, xc=xcd>>2)
    const int lin = blockIdx.x + (blockIdx.y << 6);   // gridDim.x = 64
    const int xcd = lin & 7, idx = lin >> 3;          // idx 0..63
    const int rb  = (xcd & 3) * 16 + (idx & 15);      // row-block 0..63
    const int cy  = (xcd >> 2) * 4 + (idx >> 4);      // chunk 0..7
    const int G0  = rb * 4 + wave;                    // wave's 32-row group
    const int c0g = cy * (2 * PHASES);                // first col-group (32 of them)

    __shared__ __align__(16) char smem[NBUF][2][TILEB];
    __shared__ int s_last;
    __shared__ float red[4];

    // prologue: stage both tiles of phase 0, then A loads; drain together
    stage(kb2, c0g,     wave, lane, smem[0][0]);
    stage(kb2, c0g + 1, wave, lane, smem[0][1]);

    bf16x8 a[NKF];   // 17 x 4 = 68 regs
    {
        const bf16_t* ap = qb2 + (size_t)G0 * GS + lane * 8;
        #pragma unroll
        for (int kk = 0; kk < NKF; ++kk)
            a[kk] = *(const bf16x8*)(ap + kk * 512);
    }

    float l[16];
    #pragma unroll
    for (int i = 0; i < 16; ++i) l[i] = 0.0f;

    // tile pair 0 + A in place for everyone
    asm volatile("s_waitcnt vmcnt(0) lgkmcnt(0)\n\ts_barrier" ::: "memory");

    // steady state (rolled — full unroll spilled in round 2)
    #pragma unroll 1
    for (int t = 0; t < PHASES - 1; ++t)
        PHASE(true, t);
    PHASE(false, PHASES - 1);   // drain tail

    // sum l across the 32 column-lanes (plain adds — fixed shift, no max merge)
    #pragma unroll
    for (int s = 1; s < 32; s <<= 1) {
        #pragma unroll
        for (int i = 0; i < 16; ++i)
            l[i] += __shfl_xor(l[i], s);
    }

    if (l31 == 0) {
        #pragma unroll
        for (int i = 0; i < 16; ++i) {
            const int r = (i & 3) + 8 * (i >> 2) + 4 * h;
            atomicAdd(&part_l[G0 * 32 + r], l[i]);
        }
    }

    __syncthreads();
    if (tid == 0) {
        __threadfence();
        s_last = (atomicAdd(&cnt[rb], 1u) == NCHUNK - 1) ? 1 : 0;
    }
    __syncthreads();
    if (s_last) {
        // all 8 chunk-blocks of this row-block done: finalize 128 rows
        float v = 0.0f;
        if (tid < ROWBLK) {
            const int row = rb * ROWBLK + tid;
            const float lf = atomicAdd(&part_l[row], 0.0f);   // coherent read
            v = MEXP + __builtin_amdgcn_logf(lf) - diag2[row];  // log2 domain
        }
        #pragma unroll
        for (int s = 1; s < 64; s <<= 1) v += __shfl_xor(v, s);
        if (lane == 0) red[wave] = v;
        __syncthreads();
        if (tid == 0)
            atomicAdd(out, (red[0] + red[1] + red[2] + red[3]) * (LN2 / (float)PP));
    }
}

// ---------------------------------------------------------------------------
extern "C" void kernel_launch(void* const* d_in, const int* in_sizes, int n_in,
                              void* d_out, int out_size, void* d_ws, size_t ws_size,
                              hipStream_t stream)
{
    const float* f1  = (const float*)d_in[0];   // [20000,256] f32
    const float* f2  = (const float*)d_in[1];   // [8192,256] f32
    const int*   map = (const int*)d_in[2];     // [8192] int
    float* out = (float*)d_out;

    // workspace layout (~8.98 MB)
    char* ws = (char*)d_ws;
    bf16_t*   qb2    = (bf16_t*)ws;                           // 256*8704*2 B
    bf16_t*   kb2    = qb2 + (size_t)256 * GS;                // 256*8704*2 B
    float*    diag2  = (float*)(ws + 2ull * 256 * GS * sizeof(bf16_t));
    float*    part_l = diag2 + PP;
    unsigned* cnt    = (unsigned*)(part_l + PP);

    nce_prep<<<PP / 4, 256, 0, stream>>>(f1, f2, map, qb2, kb2, diag2,
                                         part_l, cnt, out);
    nce_main<<<dim3(NROWBLK, NCHUNK), 256, 0, stream>>>(qb2, kb2, diag2,
                                                        part_l, cnt, out);
}